// Round 1
// baseline (2952.561 us; speedup 1.0000x reference)
//
#include <hip/hip_runtime.h>

#define N_B 2
#define L_L 2048
#define E_E 1024
#define H_H 16
#define D_H 64
#define QB 8
#define TB 8

__device__ __forceinline__ float dot4(float4 a, float4 b) {
  return a.x*b.x + a.y*b.y + a.z*b.z + a.w*b.w;
}

// K1: per-head QKV projections. One block per token (N*L = 4096 blocks).
// out[t,h,d] = b[d] + sum_e x[t, h*64+e] * W[d,e]   (x @ W^T + b)
// Output layout: [n][h][l][d] (head-major) for attention-friendly reads.
__global__ __launch_bounds__(256) void qkv_proj_kernel(
    const float* __restrict__ EPq, const float* __restrict__ EPk, const float* __restrict__ EPv,
    const float* __restrict__ Wq, const float* __restrict__ bq,
    const float* __restrict__ Wk, const float* __restrict__ bk,
    const float* __restrict__ Wv, const float* __restrict__ bv,
    float* __restrict__ Q, float* __restrict__ K, float* __restrict__ V)
{
  const int tid = threadIdx.x;
  const int token = blockIdx.x;
  const int n = token >> 11;       // token / L
  const int l = token & (L_L - 1);
  #pragma unroll
  for (int j = 0; j < 4; ++j) {
    const int o = j * 256 + tid;   // 0..1023 output element of this token
    const int h = o >> 6;
    const int d = o & 63;
    const float4* xq = (const float4*)(EPq + (size_t)token * E_E + h * D_H);
    const float4* xk = (const float4*)(EPk + (size_t)token * E_E + h * D_H);
    const float4* xv = (const float4*)(EPv + (size_t)token * E_E + h * D_H);
    const float4* wq = (const float4*)(Wq + d * D_H);
    const float4* wk = (const float4*)(Wk + d * D_H);
    const float4* wv = (const float4*)(Wv + d * D_H);
    float aq = bq[d], ak = bk[d], av = bv[d];
    #pragma unroll
    for (int i = 0; i < 16; ++i) {
      aq += dot4(xq[i], wq[i]);
      ak += dot4(xk[i], wk[i]);
      av += dot4(xv[i], wv[i]);
    }
    const size_t oidx = ((size_t)(n * H_H + h) * L_L + l) * D_H + d;
    Q[oidx] = aq; K[oidx] = ak; V[oidx] = av;
  }
}

// K2: attention. One block per (n,h, group of QB=8 query rows).
// grid = (N*H) * (L/QB) = 32 * 256 = 8192 blocks, 256 threads.
__global__ __launch_bounds__(256) void attn_kernel(
    const float* __restrict__ Q, const float* __restrict__ K,
    const float* __restrict__ V, float* __restrict__ A)
{
  __shared__ float qsh[QB][D_H];          // 2 KB
  __shared__ float psh[QB][L_L];          // 64 KB: scores -> probs
  __shared__ float pacc[4][QB][D_H];      // 8 KB partial PV sums
  __shared__ float linv[QB];
  const int tid = threadIdx.x;
  const int nh = blockIdx.x >> 8;         // 0..31 = n*H + h
  const int q0 = (blockIdx.x & 255) * QB;
  const float* Kb = K + (size_t)nh * L_L * D_H;
  const float* Vb = V + (size_t)nh * L_L * D_H;

  // stage the 8 q rows (contiguous in memory)
  for (int i = tid; i < QB * D_H / 4; i += 256)
    ((float4*)&qsh[0][0])[i] =
        ((const float4*)(Q + ((size_t)nh * L_L + q0) * D_H))[i];
  __syncthreads();

  // pass 1: scores[r][k] = (q_r . k_k) / 32
  for (int k = tid; k < L_L; k += 256) {
    float4 kr[16];
    const float4* Krow = (const float4*)(Kb + (size_t)k * D_H);
    #pragma unroll
    for (int i = 0; i < 16; ++i) kr[i] = Krow[i];
    #pragma unroll
    for (int r = 0; r < QB; ++r) {
      const float4* q4 = (const float4*)&qsh[r][0];
      float acc = 0.f;
      #pragma unroll
      for (int i = 0; i < 16; ++i) acc += dot4(q4[i], kr[i]);
      psh[r][k] = acc * 0.03125f;   // 1/sqrt(E) = 1/32
    }
  }
  __syncthreads();

  // softmax per row: 32 threads per row (8 rows x 32 = 256)
  {
    const int r = tid >> 5;
    const int lane = tid & 31;
    float m = -1e30f;
    for (int k = lane; k < L_L; k += 32) m = fmaxf(m, psh[r][k]);
    #pragma unroll
    for (int o = 16; o > 0; o >>= 1) m = fmaxf(m, __shfl_xor(m, o));
    float s = 0.f;
    for (int k = lane; k < L_L; k += 32) {
      float p = __expf(psh[r][k] - m);
      psh[r][k] = p;
      s += p;
    }
    #pragma unroll
    for (int o = 16; o > 0; o >>= 1) s += __shfl_xor(s, o);
    if (lane == 0) linv[r] = 1.0f / s;
  }
  __syncthreads();

  // pass 2: out[r][d] = sum_k p[r][k] * V[k][d]; 4 k-partitions
  {
    const int d = tid & 63;
    const int part = tid >> 6;
    float acc[QB];
    #pragma unroll
    for (int r = 0; r < QB; ++r) acc[r] = 0.f;
    const int kbeg = part * (L_L / 4), kend = kbeg + (L_L / 4);
    for (int k0 = kbeg; k0 < kend; k0 += 4) {
      const float v0 = Vb[(size_t)(k0 + 0) * D_H + d];
      const float v1 = Vb[(size_t)(k0 + 1) * D_H + d];
      const float v2 = Vb[(size_t)(k0 + 2) * D_H + d];
      const float v3 = Vb[(size_t)(k0 + 3) * D_H + d];
      #pragma unroll
      for (int r = 0; r < QB; ++r) {
        const float4 p4 = *(const float4*)&psh[r][k0];
        acc[r] += p4.x * v0 + p4.y * v1 + p4.z * v2 + p4.w * v3;
      }
    }
    #pragma unroll
    for (int r = 0; r < QB; ++r) pacc[part][r][d] = acc[r];
  }
  __syncthreads();

  // combine partials, normalize, write A in [n][l][E] token-major layout
  {
    const int n = nh >> 4;
    const int h = nh & 15;
    for (int i = tid; i < QB * D_H; i += 256) {
      const int r = i >> 6;
      const int dd = i & 63;
      const float o = (pacc[0][r][dd] + pacc[1][r][dd] +
                       pacc[2][r][dd] + pacc[3][r][dd]) * linv[r];
      A[((size_t)(n * L_L + q0 + r)) * E_E + h * D_H + dd] = o;
    }
  }
}

// K3: final projection out = A @ Wo^T + bo. One block per TB=8 tokens.
__global__ __launch_bounds__(256) void out_proj_kernel(
    const float* __restrict__ A, const float* __restrict__ Wo,
    const float* __restrict__ bo, float* __restrict__ out)
{
  __shared__ float xsh[TB][E_E];   // 32 KB
  const int tid = threadIdx.x;
  const size_t t0 = (size_t)blockIdx.x * TB;
  for (int i = tid; i < TB * E_E / 4; i += 256)
    ((float4*)&xsh[0][0])[i] = ((const float4*)(A + t0 * E_E))[i];
  __syncthreads();
  #pragma unroll
  for (int j = 0; j < 4; ++j) {
    const int o = j * 256 + tid;
    const float4* wrow = (const float4*)(Wo + (size_t)o * E_E);
    float acc[TB];
    #pragma unroll
    for (int t = 0; t < TB; ++t) acc[t] = 0.f;
    for (int e4 = 0; e4 < E_E / 4; ++e4) {
      const float4 w = wrow[e4];
      #pragma unroll
      for (int t = 0; t < TB; ++t)
        acc[t] += dot4(*(const float4*)&xsh[t][4 * e4], w);
    }
    const float bb = bo[o];
    #pragma unroll
    for (int t = 0; t < TB; ++t)
      out[(t0 + t) * E_E + o] = acc[t] + bb;
  }
}

extern "C" void kernel_launch(void* const* d_in, const int* in_sizes, int n_in,
                              void* d_out, int out_size, void* d_ws, size_t ws_size,
                              hipStream_t stream) {
  const float* EPq = (const float*)d_in[0];
  const float* EPk = (const float*)d_in[1];
  const float* EPv = (const float*)d_in[2];
  const float* Wq  = (const float*)d_in[3];
  const float* bq  = (const float*)d_in[4];
  const float* Wk  = (const float*)d_in[5];
  const float* bk  = (const float*)d_in[6];
  const float* Wv  = (const float*)d_in[7];
  const float* bv  = (const float*)d_in[8];
  const float* Wo  = (const float*)d_in[9];
  const float* bo  = (const float*)d_in[10];
  float* out = (float*)d_out;

  float* ws = (float*)d_ws;
  const size_t SZ = (size_t)N_B * H_H * L_L * D_H;  // 4,194,304 floats
  float* Q = ws;
  float* K = ws + SZ;
  float* V = ws + 2 * SZ;
  float* A = ws + 3 * SZ;

  qkv_proj_kernel<<<N_B * L_L, 256, 0, stream>>>(
      EPq, EPk, EPv, Wq, bq, Wk, bk, Wv, bv, Q, K, V);
  attn_kernel<<<(N_B * H_H) * (L_L / QB), 256, 0, stream>>>(Q, K, V, A);
  out_proj_kernel<<<(N_B * L_L) / TB, 256, 0, stream>>>(A, Wo, bo, out);
}

// Round 2
// 935.927 us; speedup vs baseline: 3.1547x; 3.1547x over previous
//
#include <hip/hip_runtime.h>

#define N_B 2
#define L_L 2048
#define E_E 1024
#define H_H 16
#define D_H 64
#define LDSP 72  // padded LDS row stride (ushorts): 144B -> 2-way (free) conflicts

typedef __bf16 bf16x8 __attribute__((ext_vector_type(8)));
typedef float f32x4 __attribute__((ext_vector_type(4)));
typedef short s16x8 __attribute__((ext_vector_type(8)));
typedef unsigned short u16x4 __attribute__((ext_vector_type(4)));

__device__ __forceinline__ f32x4 mfma16(bf16x8 a, bf16x8 b, f32x4 c) {
  return __builtin_amdgcn_mfma_f32_16x16x32_bf16(a, b, c, 0, 0, 0);
}

__device__ __forceinline__ unsigned short f2bf(float x) {
  unsigned int u = __float_as_uint(x);
  u = (u + 0x7fffu + ((u >> 16) & 1u)) >> 16;
  return (unsigned short)u;
}

__device__ __forceinline__ float dot4(float4 a, float4 b) {
  return a.x*b.x + a.y*b.y + a.z*b.z + a.w*b.w;
}

// K0: Wo fp32 -> bf16
__global__ __launch_bounds__(256) void cvt_wo_kernel(
    const float* __restrict__ Wo, unsigned short* __restrict__ Wob) {
  const int i = blockIdx.x * 256 + threadIdx.x;          // 262144 threads x4
  const float4 f = ((const float4*)Wo)[i];
  u16x4 v = { f2bf(f.x), f2bf(f.y), f2bf(f.z), f2bf(f.w) };
  *(u16x4*)&Wob[(size_t)i * 4] = v;
}

// K1: QKV projections (fp32 math, bf16 out). One block per token.
// Output layout: [n*H+h][l][d] bf16.
__global__ __launch_bounds__(256) void qkv_proj_kernel(
    const float* __restrict__ EPq, const float* __restrict__ EPk, const float* __restrict__ EPv,
    const float* __restrict__ Wq, const float* __restrict__ bq,
    const float* __restrict__ Wk, const float* __restrict__ bk,
    const float* __restrict__ Wv, const float* __restrict__ bv,
    unsigned short* __restrict__ Q, unsigned short* __restrict__ K, unsigned short* __restrict__ V) {
  const int tid = threadIdx.x;
  const int token = blockIdx.x;
  const int n = token >> 11;
  const int l = token & (L_L - 1);
  #pragma unroll
  for (int j = 0; j < 4; ++j) {
    const int o = j * 256 + tid;
    const int h = o >> 6;
    const int d = o & 63;
    const float4* xq = (const float4*)(EPq + (size_t)token * E_E + h * D_H);
    const float4* xk = (const float4*)(EPk + (size_t)token * E_E + h * D_H);
    const float4* xv = (const float4*)(EPv + (size_t)token * E_E + h * D_H);
    const float4* wq = (const float4*)(Wq + d * D_H);
    const float4* wk = (const float4*)(Wk + d * D_H);
    const float4* wv = (const float4*)(Wv + d * D_H);
    float aq = bq[d], ak = bk[d], av = bv[d];
    #pragma unroll
    for (int i = 0; i < 16; ++i) {
      aq += dot4(xq[i], wq[i]);
      ak += dot4(xk[i], wk[i]);
      av += dot4(xv[i], wv[i]);
    }
    const size_t oidx = ((size_t)(n * H_H + h) * L_L + l) * D_H + d;
    Q[oidx] = f2bf(aq); K[oidx] = f2bf(ak); V[oidx] = f2bf(av);
  }
}

// K1b: V [nh][l][d] -> Vt [nh][d][l]
__global__ __launch_bounds__(256) void vtrans_kernel(
    const unsigned short* __restrict__ Vb, unsigned short* __restrict__ Vtb) {
  __shared__ __attribute__((aligned(16))) unsigned short T[64][LDSP];
  const int tid = threadIdx.x;
  const int nh = blockIdx.x >> 5;
  const int l0 = (blockIdx.x & 31) * 64;
  const unsigned short* g = Vb + ((size_t)nh * L_L + l0) * D_H;
  for (int i = tid; i < 512; i += 256)
    *(s16x8*)&T[i >> 3][(i & 7) * 8] = *(const s16x8*)(g + i * 8);
  __syncthreads();
  for (int i = tid; i < 512; i += 256) {
    const int d = i >> 3, c = i & 7;
    s16x8 v;
    #pragma unroll
    for (int jj = 0; jj < 8; ++jj) v[jj] = (short)T[c * 8 + jj][d];
    *(s16x8*)(Vtb + ((size_t)nh * D_H + d) * L_L + l0 + c * 8) = v;
  }
}

// K2: flash attention with bf16 MFMA.
// grid = 32 (n*h) x 32 (q-tiles of 64). 4 waves, 16 q-rows each.
__global__ __launch_bounds__(256, 4) void attn_mfma_kernel(
    const unsigned short* __restrict__ Qb, const unsigned short* __restrict__ Kb,
    const unsigned short* __restrict__ Vtb, unsigned short* __restrict__ Ab) {
  __shared__ __attribute__((aligned(16))) unsigned short Qs[64][LDSP];
  __shared__ __attribute__((aligned(16))) unsigned short Ks[64][LDSP];
  __shared__ __attribute__((aligned(16))) unsigned short Vs[64][LDSP];  // [d][key]
  __shared__ __attribute__((aligned(16))) unsigned short Ps[4][16][LDSP];

  const int tid = threadIdx.x;
  const int wid = tid >> 6;
  const int lane = tid & 63;
  const int lr = lane & 15;
  const int lg = lane >> 4;

  const int nh = blockIdx.x >> 5;
  const int q0 = (blockIdx.x & 31) * 64;

  const unsigned short* gQ = Qb + ((size_t)nh * L_L + q0) * D_H;
  for (int i = tid; i < 512; i += 256)
    *(s16x8*)&Qs[i >> 3][(i & 7) * 8] = *(const s16x8*)(gQ + i * 8);
  __syncthreads();

  // hoisted Q A-fragments: row = lr (wave-local q), k = d = kb*32 + lg*8 + j
  const bf16x8 aQ0 = *(const bf16x8*)&Qs[wid * 16 + lr][lg * 8];
  const bf16x8 aQ1 = *(const bf16x8*)&Qs[wid * 16 + lr][32 + lg * 8];

  f32x4 acc[4] = {f32x4{0,0,0,0}, f32x4{0,0,0,0}, f32x4{0,0,0,0}, f32x4{0,0,0,0}};
  float m_run[4], l_run[4];
  #pragma unroll
  for (int r = 0; r < 4; ++r) { m_run[r] = -1e30f; l_run[r] = 0.f; }

  for (int kt = 0; kt < L_L / 64; ++kt) {
    __syncthreads();
    const unsigned short* gK = Kb + ((size_t)nh * L_L + kt * 64) * D_H;
    const unsigned short* gV = Vtb + (size_t)nh * D_H * L_L + kt * 64;
    for (int i = tid; i < 512; i += 256)
      *(s16x8*)&Ks[i >> 3][(i & 7) * 8] = *(const s16x8*)(gK + i * 8);
    for (int i = tid; i < 512; i += 256)
      *(s16x8*)&Vs[i >> 3][(i & 7) * 8] =
          *(const s16x8*)(gV + (size_t)(i >> 3) * L_L + (i & 7) * 8);
    __syncthreads();

    // QK^T: S[16q][64key] per wave; B-frag: col = key = t*16+lr, k = d
    f32x4 s[4];
    #pragma unroll
    for (int t = 0; t < 4; ++t) {
      const bf16x8 b0 = *(const bf16x8*)&Ks[t * 16 + lr][lg * 8];
      const bf16x8 b1 = *(const bf16x8*)&Ks[t * 16 + lr][32 + lg * 8];
      f32x4 c = {0, 0, 0, 0};
      c = mfma16(aQ0, b0, c);
      c = mfma16(aQ1, b1, c);
      s[t] = c;
    }

    // online softmax (natural units, scale = 1/32)
    float sv[4][4];
    #pragma unroll
    for (int t = 0; t < 4; ++t)
      #pragma unroll
      for (int r = 0; r < 4; ++r) sv[t][r] = s[t][r] * 0.03125f;

    float mt[4];
    #pragma unroll
    for (int r = 0; r < 4; ++r) {
      float v = fmaxf(fmaxf(sv[0][r], sv[1][r]), fmaxf(sv[2][r], sv[3][r]));
      v = fmaxf(v, __shfl_xor(v, 1));
      v = fmaxf(v, __shfl_xor(v, 2));
      v = fmaxf(v, __shfl_xor(v, 4));
      v = fmaxf(v, __shfl_xor(v, 8));
      mt[r] = v;
    }
    float scl[4];
    #pragma unroll
    for (int r = 0; r < 4; ++r) {
      const float mnew = fmaxf(m_run[r], mt[r]);
      scl[r] = __expf(m_run[r] - mnew);
      m_run[r] = mnew;
    }
    #pragma unroll
    for (int t = 0; t < 4; ++t)
      #pragma unroll
      for (int r = 0; r < 4; ++r) sv[t][r] = __expf(sv[t][r] - m_run[r]);
    #pragma unroll
    for (int r = 0; r < 4; ++r) {
      float su = sv[0][r] + sv[1][r] + sv[2][r] + sv[3][r];
      su += __shfl_xor(su, 1);
      su += __shfl_xor(su, 2);
      su += __shfl_xor(su, 4);
      su += __shfl_xor(su, 8);
      l_run[r] = l_run[r] * scl[r] + su;
    }
    #pragma unroll
    for (int t = 0; t < 4; ++t)
      #pragma unroll
      for (int r = 0; r < 4; ++r) acc[t][r] *= scl[r];

    // P -> per-wave LDS tile [16q][64key] (C layout: row q = lg*4+r, col = t*16+lr)
    #pragma unroll
    for (int t = 0; t < 4; ++t)
      #pragma unroll
      for (int r = 0; r < 4; ++r)
        Ps[wid][lg * 4 + r][t * 16 + lr] = f2bf(sv[t][r]);

    // PV: A-frag = P rows (q = lr), B-frag = Vt rows (d = t*16+lr, keys contiguous)
    const bf16x8 aP0 = *(const bf16x8*)&Ps[wid][lr][lg * 8];
    const bf16x8 aP1 = *(const bf16x8*)&Ps[wid][lr][32 + lg * 8];
    #pragma unroll
    for (int t = 0; t < 4; ++t) {
      const bf16x8 v0 = *(const bf16x8*)&Vs[t * 16 + lr][lg * 8];
      const bf16x8 v1 = *(const bf16x8*)&Vs[t * 16 + lr][32 + lg * 8];
      acc[t] = mfma16(aP0, v0, acc[t]);
      acc[t] = mfma16(aP1, v1, acc[t]);
    }
  }

  // epilogue: normalize, write A bf16 token-major [n][l][E]
  const int n = nh >> 4, h = nh & 15;
  float inv[4];
  #pragma unroll
  for (int r = 0; r < 4; ++r) inv[r] = 1.0f / l_run[r];
  #pragma unroll
  for (int t = 0; t < 4; ++t)
    #pragma unroll
    for (int r = 0; r < 4; ++r) {
      const int q = q0 + wid * 16 + lg * 4 + r;
      Ab[((size_t)(n * L_L + q)) * E_E + h * D_H + t * 16 + lr] = f2bf(acc[t][r] * inv[r]);
    }
}

// K4: out = A(bf16) @ Wo^T(bf16) + bo, fp32 out. 64x64 tile, 4 waves (2x2).
__global__ __launch_bounds__(256, 4) void out_gemm_kernel(
    const unsigned short* __restrict__ Ab, const unsigned short* __restrict__ Wob,
    const float* __restrict__ bo, float* __restrict__ out) {
  __shared__ __attribute__((aligned(16))) unsigned short As[64][LDSP];
  __shared__ __attribute__((aligned(16))) unsigned short Bs[64][LDSP];
  const int tid = threadIdx.x;
  const int wid = tid >> 6;
  const int lane = tid & 63;
  const int lr = lane & 15;
  const int lg = lane >> 4;
  const int m0 = (blockIdx.x >> 4) * 64;
  const int n0 = (blockIdx.x & 15) * 64;
  const int wr = wid >> 1, wc = wid & 1;

  f32x4 acc[2][2] = {{f32x4{0,0,0,0}, f32x4{0,0,0,0}}, {f32x4{0,0,0,0}, f32x4{0,0,0,0}}};

  for (int kt = 0; kt < 16; ++kt) {
    __syncthreads();
    for (int i = tid; i < 512; i += 256) {
      const int row = i >> 3, c = i & 7;
      *(s16x8*)&As[row][c * 8] =
          *(const s16x8*)(Ab + (size_t)(m0 + row) * E_E + kt * 64 + c * 8);
      *(s16x8*)&Bs[row][c * 8] =
          *(const s16x8*)(Wob + (size_t)(n0 + row) * E_E + kt * 64 + c * 8);
    }
    __syncthreads();
    #pragma unroll
    for (int kb = 0; kb < 2; ++kb) {
      const bf16x8 a0 = *(const bf16x8*)&As[wr * 32 + lr][kb * 32 + lg * 8];
      const bf16x8 a1 = *(const bf16x8*)&As[wr * 32 + 16 + lr][kb * 32 + lg * 8];
      const bf16x8 b0 = *(const bf16x8*)&Bs[wc * 32 + lr][kb * 32 + lg * 8];
      const bf16x8 b1 = *(const bf16x8*)&Bs[wc * 32 + 16 + lr][kb * 32 + lg * 8];
      acc[0][0] = mfma16(a0, b0, acc[0][0]);
      acc[0][1] = mfma16(a0, b1, acc[0][1]);
      acc[1][0] = mfma16(a1, b0, acc[1][0]);
      acc[1][1] = mfma16(a1, b1, acc[1][1]);
    }
  }
  #pragma unroll
  for (int mi = 0; mi < 2; ++mi)
    #pragma unroll
    for (int ni = 0; ni < 2; ++ni) {
      const int nn = n0 + wc * 32 + ni * 16 + lr;
      const float bb = bo[nn];
      #pragma unroll
      for (int r = 0; r < 4; ++r) {
        const int mm = m0 + wr * 32 + mi * 16 + lg * 4 + r;
        out[(size_t)mm * E_E + nn] = acc[mi][ni][r] + bb;
      }
    }
}

extern "C" void kernel_launch(void* const* d_in, const int* in_sizes, int n_in,
                              void* d_out, int out_size, void* d_ws, size_t ws_size,
                              hipStream_t stream) {
  const float* EPq = (const float*)d_in[0];
  const float* EPk = (const float*)d_in[1];
  const float* EPv = (const float*)d_in[2];
  const float* Wq  = (const float*)d_in[3];
  const float* bq  = (const float*)d_in[4];
  const float* Wk  = (const float*)d_in[5];
  const float* bk  = (const float*)d_in[6];
  const float* Wv  = (const float*)d_in[7];
  const float* bv  = (const float*)d_in[8];
  const float* Wo  = (const float*)d_in[9];
  const float* bo  = (const float*)d_in[10];
  float* out = (float*)d_out;

  unsigned short* ws = (unsigned short*)d_ws;
  const size_t SZ = (size_t)N_B * H_H * L_L * D_H;  // 4,194,304
  unsigned short* Qb  = ws;
  unsigned short* Kb  = Qb + SZ;
  unsigned short* Vb  = Kb + SZ;
  unsigned short* Vtb = Vb + SZ;
  unsigned short* Ab  = Vtb + SZ;
  unsigned short* Wob = Ab + SZ;

  cvt_wo_kernel<<<1024, 256, 0, stream>>>(Wo, Wob);
  qkv_proj_kernel<<<N_B * L_L, 256, 0, stream>>>(
      EPq, EPk, EPv, Wq, bq, Wk, bk, Wv, bv, Qb, Kb, Vb);
  vtrans_kernel<<<1024, 256, 0, stream>>>(Vb, Vtb);
  attn_mfma_kernel<<<1024, 256, 0, stream>>>(Qb, Kb, Vtb, Ab);
  out_gemm_kernel<<<1024, 256, 0, stream>>>(Ab, Wob, bo, out);
}

// Round 3
// 168.684 us; speedup vs baseline: 17.5035x; 5.5484x over previous
//
#include <hip/hip_runtime.h>

#define N_B 2
#define L_L 2048
#define E_E 1024
#define H_H 16
#define D_H 64
#define LDSP 72  // padded LDS row stride (ushorts): 144B

typedef __bf16 bf16x8 __attribute__((ext_vector_type(8)));
typedef float f32x4 __attribute__((ext_vector_type(4)));
typedef short s16x8 __attribute__((ext_vector_type(8)));
typedef unsigned short u16x4 __attribute__((ext_vector_type(4)));

__device__ __forceinline__ f32x4 mfma16(bf16x8 a, bf16x8 b, f32x4 c) {
  return __builtin_amdgcn_mfma_f32_16x16x32_bf16(a, b, c, 0, 0, 0);
}

__device__ __forceinline__ unsigned short f2bf(float x) {
  unsigned int u = __float_as_uint(x);
  u = (u + 0x7fffu + ((u >> 16) & 1u)) >> 16;
  return (unsigned short)u;
}

// K0: convert Wo (1M elems) and Wq/Wk/Wv (4096 each) to bf16.
__global__ __launch_bounds__(256) void cvt_weights_kernel(
    const float* __restrict__ Wo, const float* __restrict__ Wq,
    const float* __restrict__ Wk, const float* __restrict__ Wv,
    unsigned short* __restrict__ Wob, unsigned short* __restrict__ Wqb,
    unsigned short* __restrict__ Wkb, unsigned short* __restrict__ Wvb) {
  const int b = blockIdx.x;
  if (b < 1024) {
    const int i = b * 256 + threadIdx.x;
    const float4 f = ((const float4*)Wo)[i];
    u16x4 v = { f2bf(f.x), f2bf(f.y), f2bf(f.z), f2bf(f.w) };
    *(u16x4*)&Wob[(size_t)i * 4] = v;
  } else {
    const float* src = (b == 1024) ? Wq : (b == 1025) ? Wk : Wv;
    unsigned short* dst = (b == 1024) ? Wqb : (b == 1025) ? Wkb : Wvb;
    #pragma unroll
    for (int it = 0; it < 4; ++it) {
      const int i = it * 256 + threadIdx.x;  // 1024 float4 = 4096 floats
      const float4 f = ((const float4*)src)[i];
      u16x4 v = { f2bf(f.x), f2bf(f.y), f2bf(f.z), f2bf(f.w) };
      *(u16x4*)&dst[(size_t)i * 4] = v;
    }
  }
}

// K1: QKV projection as MFMA GEMM, one block per (n*h, 64-token tile).
// grid = 32 * 32 = 1024 blocks, 256 threads (4 waves x 16 tokens).
// Q,K out: [nh][l][d] bf16.  V out: transposed [nh][d][l] bf16 (fused).
__global__ __launch_bounds__(256) void qkv_gemm_kernel(
    const float* __restrict__ EPq, const float* __restrict__ EPk, const float* __restrict__ EPv,
    const unsigned short* __restrict__ Wqb, const unsigned short* __restrict__ Wkb,
    const unsigned short* __restrict__ Wvb,
    const float* __restrict__ bq, const float* __restrict__ bk, const float* __restrict__ bv,
    unsigned short* __restrict__ Qb, unsigned short* __restrict__ Kb,
    unsigned short* __restrict__ Vtb) {
  __shared__ __attribute__((aligned(16))) unsigned short Xs[64][LDSP];
  __shared__ __attribute__((aligned(16))) unsigned short Ws[64][LDSP];
  const int tid = threadIdx.x;
  const int wid = tid >> 6;
  const int lane = tid & 63;
  const int lr = lane & 15;
  const int lg = lane >> 4;
  const int nh = blockIdx.x >> 5;
  const int l0 = (blockIdx.x & 31) * 64;
  const int n = nh >> 4;
  const int h = nh & 15;

  #pragma unroll
  for (int mat = 0; mat < 3; ++mat) {
    const float* X = (mat == 0) ? EPq : (mat == 1) ? EPk : EPv;
    const unsigned short* W = (mat == 0) ? Wqb : (mat == 1) ? Wkb : Wvb;
    const float* bias = (mat == 0) ? bq : (mat == 1) ? bk : bv;

    // stage X tile: 64 tokens x 64 floats (head h) -> bf16 LDS
    const float* xb = X + ((size_t)(n * L_L + l0)) * E_E + h * D_H;
    #pragma unroll
    for (int it = 0; it < 4; ++it) {
      const int idx = it * 256 + tid;     // 1024 float4
      const int row = idx >> 4, c = idx & 15;
      const float4 f = *(const float4*)(xb + (size_t)row * E_E + c * 4);
      u16x4 v = { f2bf(f.x), f2bf(f.y), f2bf(f.z), f2bf(f.w) };
      *(u16x4*)&Xs[row][c * 4] = v;
    }
    // stage W (64x64 bf16)
    #pragma unroll
    for (int it = 0; it < 2; ++it) {
      const int idx = it * 256 + tid;     // 512 s16x8
      *(s16x8*)&Ws[idx >> 3][(idx & 7) * 8] =
          *(const s16x8*)(W + (size_t)(idx >> 3) * 64 + (idx & 7) * 8);
    }
    __syncthreads();

    const bf16x8 a0 = *(const bf16x8*)&Xs[wid * 16 + lr][lg * 8];
    const bf16x8 a1 = *(const bf16x8*)&Xs[wid * 16 + lr][32 + lg * 8];
    f32x4 acc[4];
    #pragma unroll
    for (int t = 0; t < 4; ++t) {
      const float bb = bias[t * 16 + lr];
      acc[t] = f32x4{bb, bb, bb, bb};
      const bf16x8 b0 = *(const bf16x8*)&Ws[t * 16 + lr][lg * 8];
      const bf16x8 b1 = *(const bf16x8*)&Ws[t * 16 + lr][32 + lg * 8];
      acc[t] = mfma16(a0, b0, acc[t]);
      acc[t] = mfma16(a1, b1, acc[t]);
    }
    __syncthreads();  // frag reads done; safe to overwrite Xs

    // C -> Xs (row = token-local, col = d)
    #pragma unroll
    for (int t = 0; t < 4; ++t)
      #pragma unroll
      for (int r = 0; r < 4; ++r)
        Xs[wid * 16 + lg * 4 + r][t * 16 + lr] = f2bf(acc[t][r]);
    __syncthreads();

    if (mat < 2) {
      unsigned short* dst = ((mat == 0) ? Qb : Kb) + ((size_t)nh * L_L + l0) * D_H;
      #pragma unroll
      for (int it = 0; it < 2; ++it) {
        const int idx = it * 256 + tid;
        const int row = idx >> 3, c = idx & 7;
        *(s16x8*)(dst + (size_t)row * D_H + c * 8) = *(s16x8*)&Xs[row][c * 8];
      }
    } else {
      // fused transpose: Vt[nh][d][l0..l0+63]; whole wave reads one LDS row
      #pragma unroll
      for (int it = 0; it < 2; ++it) {
        const int idx = it * 256 + tid;
        const int d = idx & 63, c = idx >> 6;   // c in 0..7
        s16x8 v;
        #pragma unroll
        for (int j = 0; j < 8; ++j) v[j] = (short)Xs[c * 8 + j][d];
        *(s16x8*)(Vtb + ((size_t)nh * D_H + d) * L_L + l0 + c * 8) = v;
      }
    }
    __syncthreads();  // before next mat overwrites LDS
  }
}

// K2: flash attention with bf16 MFMA.
// grid = 32 (n*h) x 32 (q-tiles of 64). 4 waves, 16 q-rows each.
__global__ __launch_bounds__(256, 4) void attn_mfma_kernel(
    const unsigned short* __restrict__ Qb, const unsigned short* __restrict__ Kb,
    const unsigned short* __restrict__ Vtb, unsigned short* __restrict__ Ab) {
  __shared__ __attribute__((aligned(16))) unsigned short Qs[64][LDSP];
  __shared__ __attribute__((aligned(16))) unsigned short Ks[64][LDSP];
  __shared__ __attribute__((aligned(16))) unsigned short Vs[64][LDSP];  // [d][key]
  __shared__ __attribute__((aligned(16))) unsigned short Ps[4][16][LDSP];

  const int tid = threadIdx.x;
  const int wid = tid >> 6;
  const int lane = tid & 63;
  const int lr = lane & 15;
  const int lg = lane >> 4;

  const int nh = blockIdx.x >> 5;
  const int q0 = (blockIdx.x & 31) * 64;

  const unsigned short* gQ = Qb + ((size_t)nh * L_L + q0) * D_H;
  for (int i = tid; i < 512; i += 256)
    *(s16x8*)&Qs[i >> 3][(i & 7) * 8] = *(const s16x8*)(gQ + i * 8);
  __syncthreads();

  const bf16x8 aQ0 = *(const bf16x8*)&Qs[wid * 16 + lr][lg * 8];
  const bf16x8 aQ1 = *(const bf16x8*)&Qs[wid * 16 + lr][32 + lg * 8];

  f32x4 acc[4] = {f32x4{0,0,0,0}, f32x4{0,0,0,0}, f32x4{0,0,0,0}, f32x4{0,0,0,0}};
  float m_run[4], l_run[4];
  #pragma unroll
  for (int r = 0; r < 4; ++r) { m_run[r] = -1e30f; l_run[r] = 0.f; }

  for (int kt = 0; kt < L_L / 64; ++kt) {
    __syncthreads();
    const unsigned short* gK = Kb + ((size_t)nh * L_L + kt * 64) * D_H;
    const unsigned short* gV = Vtb + (size_t)nh * D_H * L_L + kt * 64;
    for (int i = tid; i < 512; i += 256)
      *(s16x8*)&Ks[i >> 3][(i & 7) * 8] = *(const s16x8*)(gK + i * 8);
    for (int i = tid; i < 512; i += 256)
      *(s16x8*)&Vs[i >> 3][(i & 7) * 8] =
          *(const s16x8*)(gV + (size_t)(i >> 3) * L_L + (i & 7) * 8);
    __syncthreads();

    f32x4 s[4];
    #pragma unroll
    for (int t = 0; t < 4; ++t) {
      const bf16x8 b0 = *(const bf16x8*)&Ks[t * 16 + lr][lg * 8];
      const bf16x8 b1 = *(const bf16x8*)&Ks[t * 16 + lr][32 + lg * 8];
      f32x4 c = {0, 0, 0, 0};
      c = mfma16(aQ0, b0, c);
      c = mfma16(aQ1, b1, c);
      s[t] = c;
    }

    float sv[4][4];
    #pragma unroll
    for (int t = 0; t < 4; ++t)
      #pragma unroll
      for (int r = 0; r < 4; ++r) sv[t][r] = s[t][r] * 0.03125f;

    float mt[4];
    #pragma unroll
    for (int r = 0; r < 4; ++r) {
      float v = fmaxf(fmaxf(sv[0][r], sv[1][r]), fmaxf(sv[2][r], sv[3][r]));
      v = fmaxf(v, __shfl_xor(v, 1));
      v = fmaxf(v, __shfl_xor(v, 2));
      v = fmaxf(v, __shfl_xor(v, 4));
      v = fmaxf(v, __shfl_xor(v, 8));
      mt[r] = v;
    }
    float scl[4];
    #pragma unroll
    for (int r = 0; r < 4; ++r) {
      const float mnew = fmaxf(m_run[r], mt[r]);
      scl[r] = __expf(m_run[r] - mnew);
      m_run[r] = mnew;
    }
    #pragma unroll
    for (int t = 0; t < 4; ++t)
      #pragma unroll
      for (int r = 0; r < 4; ++r) sv[t][r] = __expf(sv[t][r] - m_run[r]);
    #pragma unroll
    for (int r = 0; r < 4; ++r) {
      float su = sv[0][r] + sv[1][r] + sv[2][r] + sv[3][r];
      su += __shfl_xor(su, 1);
      su += __shfl_xor(su, 2);
      su += __shfl_xor(su, 4);
      su += __shfl_xor(su, 8);
      l_run[r] = l_run[r] * scl[r] + su;
    }
    #pragma unroll
    for (int t = 0; t < 4; ++t)
      #pragma unroll
      for (int r = 0; r < 4; ++r) acc[t][r] *= scl[r];

    #pragma unroll
    for (int t = 0; t < 4; ++t)
      #pragma unroll
      for (int r = 0; r < 4; ++r)
        Ps[wid][lg * 4 + r][t * 16 + lr] = f2bf(sv[t][r]);

    const bf16x8 aP0 = *(const bf16x8*)&Ps[wid][lr][lg * 8];
    const bf16x8 aP1 = *(const bf16x8*)&Ps[wid][lr][32 + lg * 8];
    #pragma unroll
    for (int t = 0; t < 4; ++t) {
      const bf16x8 v0 = *(const bf16x8*)&Vs[t * 16 + lr][lg * 8];
      const bf16x8 v1 = *(const bf16x8*)&Vs[t * 16 + lr][32 + lg * 8];
      acc[t] = mfma16(aP0, v0, acc[t]);
      acc[t] = mfma16(aP1, v1, acc[t]);
    }
  }

  const int n = nh >> 4, h = nh & 15;
  float inv[4];
  #pragma unroll
  for (int r = 0; r < 4; ++r) inv[r] = 1.0f / l_run[r];
  #pragma unroll
  for (int t = 0; t < 4; ++t)
    #pragma unroll
    for (int r = 0; r < 4; ++r) {
      const int q = q0 + wid * 16 + lg * 4 + r;
      Ab[((size_t)(n * L_L + q)) * E_E + h * D_H + t * 16 + lr] = f2bf(acc[t][r] * inv[r]);
    }
}

// K3: out = A(bf16) @ Wo^T(bf16) + bo, fp32 out. 64x64 tile, 4 waves (2x2).
__global__ __launch_bounds__(256, 4) void out_gemm_kernel(
    const unsigned short* __restrict__ Ab, const unsigned short* __restrict__ Wob,
    const float* __restrict__ bo, float* __restrict__ out) {
  __shared__ __attribute__((aligned(16))) unsigned short As[64][LDSP];
  __shared__ __attribute__((aligned(16))) unsigned short Bs[64][LDSP];
  const int tid = threadIdx.x;
  const int wid = tid >> 6;
  const int lane = tid & 63;
  const int lr = lane & 15;
  const int lg = lane >> 4;
  const int m0 = (blockIdx.x >> 4) * 64;
  const int n0 = (blockIdx.x & 15) * 64;
  const int wr = wid >> 1, wc = wid & 1;

  f32x4 acc[2][2] = {{f32x4{0,0,0,0}, f32x4{0,0,0,0}}, {f32x4{0,0,0,0}, f32x4{0,0,0,0}}};

  for (int kt = 0; kt < 16; ++kt) {
    __syncthreads();
    for (int i = tid; i < 512; i += 256) {
      const int row = i >> 3, c = i & 7;
      *(s16x8*)&As[row][c * 8] =
          *(const s16x8*)(Ab + (size_t)(m0 + row) * E_E + kt * 64 + c * 8);
      *(s16x8*)&Bs[row][c * 8] =
          *(const s16x8*)(Wob + (size_t)(n0 + row) * E_E + kt * 64 + c * 8);
    }
    __syncthreads();
    #pragma unroll
    for (int kb = 0; kb < 2; ++kb) {
      const bf16x8 a0 = *(const bf16x8*)&As[wr * 32 + lr][kb * 32 + lg * 8];
      const bf16x8 a1 = *(const bf16x8*)&As[wr * 32 + 16 + lr][kb * 32 + lg * 8];
      const bf16x8 b0 = *(const bf16x8*)&Bs[wc * 32 + lr][kb * 32 + lg * 8];
      const bf16x8 b1 = *(const bf16x8*)&Bs[wc * 32 + 16 + lr][kb * 32 + lg * 8];
      acc[0][0] = mfma16(a0, b0, acc[0][0]);
      acc[0][1] = mfma16(a0, b1, acc[0][1]);
      acc[1][0] = mfma16(a1, b0, acc[1][0]);
      acc[1][1] = mfma16(a1, b1, acc[1][1]);
    }
  }
  #pragma unroll
  for (int mi = 0; mi < 2; ++mi)
    #pragma unroll
    for (int ni = 0; ni < 2; ++ni) {
      const int nn = n0 + wc * 32 + ni * 16 + lr;
      const float bb = bo[nn];
      #pragma unroll
      for (int r = 0; r < 4; ++r) {
        const int mm = m0 + wr * 32 + mi * 16 + lg * 4 + r;
        out[(size_t)mm * E_E + nn] = acc[mi][ni][r] + bb;
      }
    }
}

extern "C" void kernel_launch(void* const* d_in, const int* in_sizes, int n_in,
                              void* d_out, int out_size, void* d_ws, size_t ws_size,
                              hipStream_t stream) {
  const float* EPq = (const float*)d_in[0];
  const float* EPk = (const float*)d_in[1];
  const float* EPv = (const float*)d_in[2];
  const float* Wq  = (const float*)d_in[3];
  const float* bq  = (const float*)d_in[4];
  const float* Wk  = (const float*)d_in[5];
  const float* bk  = (const float*)d_in[6];
  const float* Wv  = (const float*)d_in[7];
  const float* bv  = (const float*)d_in[8];
  const float* Wo  = (const float*)d_in[9];
  const float* bo  = (const float*)d_in[10];
  float* out = (float*)d_out;

  unsigned short* ws = (unsigned short*)d_ws;
  const size_t SZ = (size_t)N_B * H_H * L_L * D_H;  // 4,194,304
  unsigned short* Qb  = ws;
  unsigned short* Kb  = Qb + SZ;
  unsigned short* Vtb = Kb + SZ;
  unsigned short* Ab  = Vtb + SZ;
  unsigned short* Wob = Ab + SZ;         // 1,048,576
  unsigned short* Wqb = Wob + (size_t)E_E * E_E;
  unsigned short* Wkb = Wqb + D_H * D_H;
  unsigned short* Wvb = Wkb + D_H * D_H;

  cvt_weights_kernel<<<1027, 256, 0, stream>>>(Wo, Wq, Wk, Wv, Wob, Wqb, Wkb, Wvb);
  qkv_gemm_kernel<<<1024, 256, 0, stream>>>(
      EPq, EPk, EPv, Wqb, Wkb, Wvb, bq, bk, bv, Qb, Kb, Vtb);
  attn_mfma_kernel<<<1024, 256, 0, stream>>>(Qb, Kb, Vtb, Ab);
  out_gemm_kernel<<<1024, 256, 0, stream>>>(Ab, Wob, bo, out);
}

// Round 4
// 117.815 us; speedup vs baseline: 25.0610x; 1.4318x over previous
//
#include <hip/hip_runtime.h>

#define N_B 2
#define L_L 2048
#define E_E 1024
#define H_H 16
#define D_H 64
#define LDSP 72  // padded LDS row stride (ushorts) for qkv/out kernels

typedef __bf16 bf16x8 __attribute__((ext_vector_type(8)));
typedef float f32x4 __attribute__((ext_vector_type(4)));
typedef short s16x8 __attribute__((ext_vector_type(8)));
typedef unsigned short u16x4 __attribute__((ext_vector_type(4)));

__device__ __forceinline__ f32x4 mfma16(bf16x8 a, bf16x8 b, f32x4 c) {
  return __builtin_amdgcn_mfma_f32_16x16x32_bf16(a, b, c, 0, 0, 0);
}

__device__ __forceinline__ unsigned short f2bf(float x) {
  unsigned int u = __float_as_uint(x);
  u = (u + 0x7fffu + ((u >> 16) & 1u)) >> 16;
  return (unsigned short)u;
}

__device__ __forceinline__ unsigned int cvtpk(float lo, float hi) {
  unsigned int r;
  asm("v_cvt_pk_bf16_f32 %0, %1, %2" : "=v"(r) : "v"(lo), "v"(hi));
  return r;
}

__device__ __forceinline__ float dot4(float4 a, float4 b) {
  return a.x*b.x + a.y*b.y + a.z*b.z + a.w*b.w;
}

// K0: convert Wo (1M elems) and Wq/Wk/Wv (4096 each) to bf16.
__global__ __launch_bounds__(256) void cvt_weights_kernel(
    const float* __restrict__ Wo, const float* __restrict__ Wq,
    const float* __restrict__ Wk, const float* __restrict__ Wv,
    unsigned short* __restrict__ Wob, unsigned short* __restrict__ Wqb,
    unsigned short* __restrict__ Wkb, unsigned short* __restrict__ Wvb) {
  const int b = blockIdx.x;
  if (b < 1024) {
    const int i = b * 256 + threadIdx.x;
    const float4 f = ((const float4*)Wo)[i];
    u16x4 v = { f2bf(f.x), f2bf(f.y), f2bf(f.z), f2bf(f.w) };
    *(u16x4*)&Wob[(size_t)i * 4] = v;
  } else {
    const float* src = (b == 1024) ? Wq : (b == 1025) ? Wk : Wv;
    unsigned short* dst = (b == 1024) ? Wqb : (b == 1025) ? Wkb : Wvb;
    #pragma unroll
    for (int it = 0; it < 4; ++it) {
      const int i = it * 256 + threadIdx.x;
      const float4 f = ((const float4*)src)[i];
      u16x4 v = { f2bf(f.x), f2bf(f.y), f2bf(f.z), f2bf(f.w) };
      *(u16x4*)&dst[(size_t)i * 4] = v;
    }
  }
}

// K1: QKV projection as MFMA GEMM (unchanged from round 3).
__global__ __launch_bounds__(256) void qkv_gemm_kernel(
    const float* __restrict__ EPq, const float* __restrict__ EPk, const float* __restrict__ EPv,
    const unsigned short* __restrict__ Wqb, const unsigned short* __restrict__ Wkb,
    const unsigned short* __restrict__ Wvb,
    const float* __restrict__ bq, const float* __restrict__ bk, const float* __restrict__ bv,
    unsigned short* __restrict__ Qb, unsigned short* __restrict__ Kb,
    unsigned short* __restrict__ Vtb) {
  __shared__ __attribute__((aligned(16))) unsigned short Xs[64][LDSP];
  __shared__ __attribute__((aligned(16))) unsigned short Ws[64][LDSP];
  const int tid = threadIdx.x;
  const int wid = tid >> 6;
  const int lane = tid & 63;
  const int lr = lane & 15;
  const int lg = lane >> 4;
  const int nh = blockIdx.x >> 5;
  const int l0 = (blockIdx.x & 31) * 64;
  const int n = nh >> 4;
  const int h = nh & 15;

  #pragma unroll
  for (int mat = 0; mat < 3; ++mat) {
    const float* X = (mat == 0) ? EPq : (mat == 1) ? EPk : EPv;
    const unsigned short* W = (mat == 0) ? Wqb : (mat == 1) ? Wkb : Wvb;
    const float* bias = (mat == 0) ? bq : (mat == 1) ? bk : bv;

    const float* xb = X + ((size_t)(n * L_L + l0)) * E_E + h * D_H;
    #pragma unroll
    for (int it = 0; it < 4; ++it) {
      const int idx = it * 256 + tid;
      const int row = idx >> 4, c = idx & 15;
      const float4 f = *(const float4*)(xb + (size_t)row * E_E + c * 4);
      u16x4 v = { f2bf(f.x), f2bf(f.y), f2bf(f.z), f2bf(f.w) };
      *(u16x4*)&Xs[row][c * 4] = v;
    }
    #pragma unroll
    for (int it = 0; it < 2; ++it) {
      const int idx = it * 256 + tid;
      *(s16x8*)&Ws[idx >> 3][(idx & 7) * 8] =
          *(const s16x8*)(W + (size_t)(idx >> 3) * 64 + (idx & 7) * 8);
    }
    __syncthreads();

    const bf16x8 a0 = *(const bf16x8*)&Xs[wid * 16 + lr][lg * 8];
    const bf16x8 a1 = *(const bf16x8*)&Xs[wid * 16 + lr][32 + lg * 8];
    f32x4 acc[4];
    #pragma unroll
    for (int t = 0; t < 4; ++t) {
      const float bb = bias[t * 16 + lr];
      acc[t] = f32x4{bb, bb, bb, bb};
      const bf16x8 b0 = *(const bf16x8*)&Ws[t * 16 + lr][lg * 8];
      const bf16x8 b1 = *(const bf16x8*)&Ws[t * 16 + lr][32 + lg * 8];
      acc[t] = mfma16(a0, b0, acc[t]);
      acc[t] = mfma16(a1, b1, acc[t]);
    }
    __syncthreads();

    #pragma unroll
    for (int t = 0; t < 4; ++t)
      #pragma unroll
      for (int r = 0; r < 4; ++r)
        Xs[wid * 16 + lg * 4 + r][t * 16 + lr] = f2bf(acc[t][r]);
    __syncthreads();

    if (mat < 2) {
      unsigned short* dst = ((mat == 0) ? Qb : Kb) + ((size_t)nh * L_L + l0) * D_H;
      #pragma unroll
      for (int it = 0; it < 2; ++it) {
        const int idx = it * 256 + tid;
        const int row = idx >> 3, c = idx & 7;
        *(s16x8*)(dst + (size_t)row * D_H + c * 8) = *(s16x8*)&Xs[row][c * 8];
      }
    } else {
      #pragma unroll
      for (int it = 0; it < 2; ++it) {
        const int idx = it * 256 + tid;
        const int d = idx & 63, c = idx >> 6;
        s16x8 v;
        #pragma unroll
        for (int j = 0; j < 8; ++j) v[j] = (short)Xs[c * 8 + j][d];
        *(s16x8*)(Vtb + ((size_t)nh * D_H + d) * L_L + l0 + c * 8) = v;
      }
    }
    __syncthreads();
  }
}

// K2: flash attention, swapped-QK^T, 32 q/wave, dbuf swizzled K/V LDS.
// grid = 512 blocks (32 nh x 16 q-tiles of 128), 256 threads (4 waves x 32 q).
__global__ __launch_bounds__(256, 3) void attn_mfma_kernel(
    const unsigned short* __restrict__ Qb, const unsigned short* __restrict__ Kb,
    const unsigned short* __restrict__ Vtb, unsigned short* __restrict__ Ab) {
  __shared__ __attribute__((aligned(16))) unsigned short KS[2][64][64];
  __shared__ __attribute__((aligned(16))) unsigned short VS[2][64][64];
  __shared__ __attribute__((aligned(16))) unsigned short PS[4][32][64];

  const int tid = threadIdx.x;
  const int wid = tid >> 6;
  const int lane = tid & 63;
  const int lr = lane & 15;
  const int lg = lane >> 4;

  // XCD-bijective swizzle: 512 blocks, 8 XCDs, 64 per XCD -> 4 heads/XCD
  const int bid = ((blockIdx.x & 7) << 6) + (blockIdx.x >> 3);
  const int nh = bid >> 4;
  const int q0b = (bid & 15) << 7;       // 128-row q tile per block
  const int q0w = q0b + wid * 32;        // 32 rows per wave

  const unsigned short* gQ = Qb + ((size_t)nh * L_L + q0w) * D_H;
  const unsigned short* gKbase = Kb + (size_t)nh * L_L * D_H;
  const unsigned short* gVbase = Vtb + (size_t)nh * D_H * L_L;

  // Q fragments (B-operand): bQ[qb][c2] = Q[q0w+qb*16+lr][c2*32+lg*8 ..+8]
  bf16x8 bQ[2][2];
  #pragma unroll
  for (int qb = 0; qb < 2; ++qb)
    #pragma unroll
    for (int c2 = 0; c2 < 2; ++c2)
      bQ[qb][c2] = *(const bf16x8*)(gQ + (qb * 16 + lr) * D_H + c2 * 32 + lg * 8);

  const s16x8 ones16 = {0x3F80,0x3F80,0x3F80,0x3F80,0x3F80,0x3F80,0x3F80,0x3F80};
  const bf16x8 ones = *(const bf16x8*)&ones16;

  const int srow0 = tid >> 3, sc0 = tid & 7;            // staging chunk 0
  const int srow1 = (tid + 256) >> 3, sc1 = tid & 7;    // staging chunk 1
  char* const ksw0 = (char*)&KS[0][0][0] + srow0 * 128 + ((sc0 ^ (srow0 & 7)) << 4);
  char* const ksw1 = (char*)&KS[0][0][0] + srow1 * 128 + ((sc1 ^ (srow1 & 7)) << 4);
  char* const vsw0 = (char*)&VS[0][0][0] + srow0 * 128 + ((sc0 ^ (srow0 & 7)) << 4);
  char* const vsw1 = (char*)&VS[0][0][0] + srow1 * 128 + ((sc1 ^ (srow1 & 7)) << 4);

  // prologue: stage tile 0 into buffer 0
  {
    const unsigned short* gK = gKbase;           // kt = 0
    const unsigned short* gV = gVbase;
    s16x8 k0 = *(const s16x8*)(gK + srow0 * 64 + sc0 * 8);
    s16x8 k1 = *(const s16x8*)(gK + srow1 * 64 + sc1 * 8);
    s16x8 v0 = *(const s16x8*)(gV + (size_t)srow0 * L_L + sc0 * 8);
    s16x8 v1 = *(const s16x8*)(gV + (size_t)srow1 * L_L + sc1 * 8);
    *(s16x8*)ksw0 = k0; *(s16x8*)ksw1 = k1;
    *(s16x8*)vsw0 = v0; *(s16x8*)vsw1 = v1;
  }
  __syncthreads();

  f32x4 acc0[4] = {f32x4{0,0,0,0},f32x4{0,0,0,0},f32x4{0,0,0,0},f32x4{0,0,0,0}};
  f32x4 acc1[4] = {f32x4{0,0,0,0},f32x4{0,0,0,0},f32x4{0,0,0,0},f32x4{0,0,0,0}};
  f32x4 lacc0 = {0,0,0,0}, lacc1 = {0,0,0,0};
  float m0 = -1e30f, m1 = -1e30f;
  const float SC = 0.03125f * 1.44269504089f;  // (1/sqrt(E)) * log2(e)

  char* const myPs = (char*)&PS[0][0][0] + wid * 4096;
  int cur = 0;

  for (int kt = 0; kt < L_L / 64; ++kt) {
    // STAGE_LOAD: issue next tile's global loads (T14 async split)
    const int nxt = (kt + 1 < L_L / 64) ? kt + 1 : kt;
    const unsigned short* gK = gKbase + (size_t)nxt * 64 * D_H;
    const unsigned short* gV = gVbase + (size_t)nxt * 64;
    const s16x8 kr0 = *(const s16x8*)(gK + srow0 * 64 + sc0 * 8);
    const s16x8 kr1 = *(const s16x8*)(gK + srow1 * 64 + sc1 * 8);
    const s16x8 vr0 = *(const s16x8*)(gV + (size_t)srow0 * L_L + sc0 * 8);
    const s16x8 vr1 = *(const s16x8*)(gV + (size_t)srow1 * L_L + sc1 * 8);

    const char* Kcur = (const char*)&KS[cur][0][0];
    const char* Vcur = (const char*)&VS[cur][0][0];

    // QK^T swapped: S[key][q]; lane holds key = kb*16+4lg+r for q = qb*16+lr
    float sv0[16], sv1[16];
    #pragma unroll
    for (int kb = 0; kb < 4; ++kb) {
      const int row = kb * 16 + lr;
      const bf16x8 a0 = *(const bf16x8*)(Kcur + row * 128 + (((lg) ^ (row & 7)) << 4));
      const bf16x8 a1 = *(const bf16x8*)(Kcur + row * 128 + (((4 + lg) ^ (row & 7)) << 4));
      f32x4 c0 = {0,0,0,0};
      c0 = mfma16(a0, bQ[0][0], c0); c0 = mfma16(a1, bQ[0][1], c0);
      f32x4 c1 = {0,0,0,0};
      c1 = mfma16(a0, bQ[1][0], c1); c1 = mfma16(a1, bQ[1][1], c1);
      #pragma unroll
      for (int r = 0; r < 4; ++r) { sv0[kb*4+r] = c0[r] * SC; sv1[kb*4+r] = c1[r] * SC; }
    }

    // in-lane max over this lane's 16 keys per q
    float mt0 = sv0[0], mt1 = sv1[0];
    #pragma unroll
    for (int j = 1; j < 16; ++j) { mt0 = fmaxf(mt0, sv0[j]); mt1 = fmaxf(mt1, sv1[j]); }

    // defer-max: skip cross-lane reduce + rescale when growth small (T13)
    const bool defer = (mt0 - m0 <= 8.0f) && (mt1 - m1 <= 8.0f);
    if (!__all(defer)) {
      float v0 = fmaxf(mt0, __shfl_xor(mt0, 16)); v0 = fmaxf(v0, __shfl_xor(v0, 32));
      float v1 = fmaxf(mt1, __shfl_xor(mt1, 16)); v1 = fmaxf(v1, __shfl_xor(v1, 32));
      const float mn0 = fmaxf(m0, v0), mn1 = fmaxf(m1, v1);
      const float sc0f = exp2f(m0 - mn0), sc1f = exp2f(m1 - mn1);
      m0 = mn0; m1 = mn1;
      #pragma unroll
      for (int r = 0; r < 4; ++r) {
        const float sa0 = __shfl(sc0f, 4 * lg + r);
        const float sa1 = __shfl(sc1f, 4 * lg + r);
        #pragma unroll
        for (int t = 0; t < 4; ++t) { acc0[t][r] *= sa0; acc1[t][r] *= sa1; }
        lacc0[r] *= sa0; lacc1[r] *= sa1;
      }
    }

    #pragma unroll
    for (int j = 0; j < 16; ++j) { sv0[j] = exp2f(sv0[j] - m0); sv1[j] = exp2f(sv1[j] - m1); }

    // pack P -> per-wave swizzled LDS tile [32 q][64 key]
    #pragma unroll
    for (int kb = 0; kb < 4; ++kb)
      #pragma unroll
      for (int i = 0; i < 2; ++i) {
        const int off = (kb * 32 + 8 * lg + 4 * i) ^ ((lr & 7) << 4);
        *(unsigned int*)(myPs + lr * 128 + off)        = cvtpk(sv0[kb*4+2*i], sv0[kb*4+2*i+1]);
        *(unsigned int*)(myPs + (16 + lr) * 128 + off) = cvtpk(sv1[kb*4+2*i], sv1[kb*4+2*i+1]);
      }

    // P A-frags + row-sum via ones-MFMA + PV
    bf16x8 aP0[2], aP1[2];
    #pragma unroll
    for (int kc = 0; kc < 2; ++kc) {
      const int off = ((kc * 4 + lg) ^ (lr & 7)) << 4;
      aP0[kc] = *(const bf16x8*)(myPs + lr * 128 + off);
      aP1[kc] = *(const bf16x8*)(myPs + (16 + lr) * 128 + off);
    }
    lacc0 = mfma16(aP0[0], ones, lacc0); lacc0 = mfma16(aP0[1], ones, lacc0);
    lacc1 = mfma16(aP1[0], ones, lacc1); lacc1 = mfma16(aP1[1], ones, lacc1);
    #pragma unroll
    for (int t = 0; t < 4; ++t) {
      const int row = t * 16 + lr;
      const bf16x8 v0 = *(const bf16x8*)(Vcur + row * 128 + (((lg) ^ (row & 7)) << 4));
      const bf16x8 v1 = *(const bf16x8*)(Vcur + row * 128 + (((4 + lg) ^ (row & 7)) << 4));
      acc0[t] = mfma16(aP0[0], v0, acc0[t]); acc0[t] = mfma16(aP0[1], v1, acc0[t]);
      acc1[t] = mfma16(aP1[0], v0, acc1[t]); acc1[t] = mfma16(aP1[1], v1, acc1[t]);
    }

    // STAGE_WRITE next tile into the other buffer, then single barrier
    {
      char* const o = (char*)&KS[cur ^ 1][0][0] - (char*)&KS[0][0][0] + (char*)0;
      const size_t boff = (size_t)(cur ^ 1) * 64 * 64 * 2;
      *(s16x8*)(ksw0 + boff) = kr0; *(s16x8*)(ksw1 + boff) = kr1;
      *(s16x8*)(vsw0 + boff) = vr0; *(s16x8*)(vsw1 + boff) = vr1;
      (void)o;
    }
    __syncthreads();
    cur ^= 1;
  }

  // epilogue: normalize, write A bf16 token-major [n][l][E]
  const int n = nh >> 4, h = nh & 15;
  #pragma unroll
  for (int qb = 0; qb < 2; ++qb) {
    const f32x4& la = qb ? lacc1 : lacc0;
    f32x4* ac = qb ? acc1 : acc0;
    f32x4 inv;
    #pragma unroll
    for (int r = 0; r < 4; ++r) inv[r] = 1.0f / la[r];
    const int qbase = q0w + qb * 16 + 4 * lg;
    #pragma unroll
    for (int t = 0; t < 4; ++t)
      #pragma unroll
      for (int r = 0; r < 4; ++r)
        Ab[((size_t)(n * L_L + qbase + r)) * E_E + h * D_H + t * 16 + lr] =
            f2bf(ac[t][r] * inv[r]);
  }
}

// K3: out = A(bf16) @ Wo^T(bf16) + bo, fp32 out (unchanged from round 3).
__global__ __launch_bounds__(256, 4) void out_gemm_kernel(
    const unsigned short* __restrict__ Ab, const unsigned short* __restrict__ Wob,
    const float* __restrict__ bo, float* __restrict__ out) {
  __shared__ __attribute__((aligned(16))) unsigned short As[64][LDSP];
  __shared__ __attribute__((aligned(16))) unsigned short Bs[64][LDSP];
  const int tid = threadIdx.x;
  const int wid = tid >> 6;
  const int lane = tid & 63;
  const int lr = lane & 15;
  const int lg = lane >> 4;
  const int m0 = (blockIdx.x >> 4) * 64;
  const int n0 = (blockIdx.x & 15) * 64;
  const int wr = wid >> 1, wc = wid & 1;

  f32x4 acc[2][2] = {{f32x4{0,0,0,0}, f32x4{0,0,0,0}}, {f32x4{0,0,0,0}, f32x4{0,0,0,0}}};

  for (int kt = 0; kt < 16; ++kt) {
    __syncthreads();
    for (int i = tid; i < 512; i += 256) {
      const int row = i >> 3, c = i & 7;
      *(s16x8*)&As[row][c * 8] =
          *(const s16x8*)(Ab + (size_t)(m0 + row) * E_E + kt * 64 + c * 8);
      *(s16x8*)&Bs[row][c * 8] =
          *(const s16x8*)(Wob + (size_t)(n0 + row) * E_E + kt * 64 + c * 8);
    }
    __syncthreads();
    #pragma unroll
    for (int kb = 0; kb < 2; ++kb) {
      const bf16x8 a0 = *(const bf16x8*)&As[wr * 32 + lr][kb * 32 + lg * 8];
      const bf16x8 a1 = *(const bf16x8*)&As[wr * 32 + 16 + lr][kb * 32 + lg * 8];
      const bf16x8 b0 = *(const bf16x8*)&Bs[wc * 32 + lr][kb * 32 + lg * 8];
      const bf16x8 b1 = *(const bf16x8*)&Bs[wc * 32 + 16 + lr][kb * 32 + lg * 8];
      acc[0][0] = mfma16(a0, b0, acc[0][0]);
      acc[0][1] = mfma16(a0, b1, acc[0][1]);
      acc[1][0] = mfma16(a1, b0, acc[1][0]);
      acc[1][1] = mfma16(a1, b1, acc[1][1]);
    }
  }
  #pragma unroll
  for (int mi = 0; mi < 2; ++mi)
    #pragma unroll
    for (int ni = 0; ni < 2; ++ni) {
      const int nn = n0 + wc * 32 + ni * 16 + lr;
      const float bb = bo[nn];
      #pragma unroll
      for (int r = 0; r < 4; ++r) {
        const int mm = m0 + wr * 32 + mi * 16 + lg * 4 + r;
        out[(size_t)mm * E_E + nn] = acc[mi][ni][r] + bb;
      }
    }
}

extern "C" void kernel_launch(void* const* d_in, const int* in_sizes, int n_in,
                              void* d_out, int out_size, void* d_ws, size_t ws_size,
                              hipStream_t stream) {
  const float* EPq = (const float*)d_in[0];
  const float* EPk = (const float*)d_in[1];
  const float* EPv = (const float*)d_in[2];
  const float* Wq  = (const float*)d_in[3];
  const float* bq  = (const float*)d_in[4];
  const float* Wk  = (const float*)d_in[5];
  const float* bk  = (const float*)d_in[6];
  const float* Wv  = (const float*)d_in[7];
  const float* bv  = (const float*)d_in[8];
  const float* Wo  = (const float*)d_in[9];
  const float* bo  = (const float*)d_in[10];
  float* out = (float*)d_out;

  unsigned short* ws = (unsigned short*)d_ws;
  const size_t SZ = (size_t)N_B * H_H * L_L * D_H;  // 4,194,304
  unsigned short* Qb  = ws;
  unsigned short* Kb  = Qb + SZ;
  unsigned short* Vtb = Kb + SZ;
  unsigned short* Ab  = Vtb + SZ;
  unsigned short* Wob = Ab + SZ;
  unsigned short* Wqb = Wob + (size_t)E_E * E_E;
  unsigned short* Wkb = Wqb + D_H * D_H;
  unsigned short* Wvb = Wkb + D_H * D_H;

  cvt_weights_kernel<<<1027, 256, 0, stream>>>(Wo, Wq, Wk, Wv, Wob, Wqb, Wkb, Wvb);
  qkv_gemm_kernel<<<1024, 256, 0, stream>>>(
      EPq, EPk, EPv, Wqb, Wkb, Wvb, bq, bk, bv, Qb, Kb, Vtb);
  attn_mfma_kernel<<<512, 256, 0, stream>>>(Qb, Kb, Vtb, Ab);
  out_gemm_kernel<<<1024, 256, 0, stream>>>(Ab, Wob, bo, out);
}